// Round 16
// baseline (265.523 us; speedup 1.0000x reference)
//
#include <hip/hip_runtime.h>
#include <hip/hip_bf16.h>

// ---------------------------------------------------------------------------
// QuantAttention: x[256,196,512] -> qkv -> windowed attn (+rel-pos bias) -> proj
// bf16 MFMA everywhere. GEMMs: 256x256 tile, BK=64 K-tiles, 4 fine phases per
// K-tile, deep-slack counted vmcnt(8) staging, XOR-swizzled LDS, setprio.
// qkv outputs row-major [bh][196][32]; attn transposes V into LDS with a
// granule-XOR swizzle; per-nt bias quads prefetched into registers.
// Prologue (3x cvt + bias gather) fused into ONE kernel. gemm<1> epilogue:
// row-contiguous nontemporal stores (fix 1.5x write amplification).
// Workspace layout:
//   [0)            x_bf16 (aliased later as attn_out bf16)   51,380,224 B
//   [51380224)     qkv_w bf16                                 1,572,864 B
//   [52953088)     proj_w bf16                                  524,288 B
//   [53477376)     q bf16 [bh][196][32] (scale folded)       51,380,224 B
//   [104857600)    k bf16 [bh][196][32]                      51,380,224 B
//   [156237824)    v bf16 [bh][196][32]                      51,380,224 B
//   [217055232)    bias bf16 [h][13][14][64][4] (swapped)     1,490,944 B
// ---------------------------------------------------------------------------

typedef unsigned short u16;
typedef unsigned int u32;
typedef __attribute__((ext_vector_type(8))) short bf16x8;
typedef __attribute__((ext_vector_type(4))) float f32x4;

#define AS1 __attribute__((address_space(1)))
#define AS3 __attribute__((address_space(3)))

__device__ __forceinline__ u16 f2bf(float f) {
  union { float f; unsigned u; } c; c.f = f;
  unsigned r = ((c.u >> 16) & 1u) + 0x7fffu;   // round-to-nearest-even
  return (u16)((c.u + r) >> 16);
}

__device__ __forceinline__ void cvt4(const float* __restrict__ in,
                                     u16* __restrict__ out, int i, int n) {
  if (i >= n) return;
  float4 v = *(const float4*)(in + i);
  ushort4 o;
  o.x = f2bf(v.x); o.y = f2bf(v.y); o.z = f2bf(v.z); o.w = f2bf(v.w);
  *(ushort4*)(out + i) = o;
}

// ---- fused prologue: cvt x / qkv_w / proj_w + rel-pos bias pre-gather -----
// blocks [0,25088): x; [25088,25856): qkv_w; [25856,26112): proj_w;
// [26112,29024): bias bf16 [h][13][14][64][4] in SWAPPED C-frag order
// (n = nt*16+(lane&15) clamped, m = mt*16+(lane>>4)*4+r; m>=196 -> -1e30).
__global__ __launch_bounds__(256) void prep_fused(
    const float* __restrict__ x, const float* __restrict__ qkv_w,
    const float* __restrict__ proj_w, const float* __restrict__ table,
    const int* __restrict__ idx, u16* __restrict__ xb, u16* __restrict__ qwb,
    u16* __restrict__ pwb, u16* __restrict__ outb) {
  const int b = blockIdx.x, tid = threadIdx.x;
  if (b < 25088) {
    cvt4(x, xb, (b * 256 + tid) * 4, 25690112);
  } else if (b < 25856) {
    cvt4(qkv_w, qwb, ((b - 25088) * 256 + tid) * 4, 786432);
  } else if (b < 26112) {
    cvt4(proj_w, pwb, ((b - 25856) * 256 + tid) * 4, 262144);
  } else {
    int e = (b - 26112) * 256 + tid;           // < 745472
    int r = e & 3, lane = (e >> 2) & 63, rest = e >> 8;
    int mt = rest % 14; rest /= 14;
    int nt = rest % 13; int h = rest / 13;
    int n = nt * 16 + (lane & 15);
    int m = mt * 16 + ((lane >> 4) << 2) + r;
    float v;
    if (m < 196) {
      int nc = n < 196 ? n : 195;
      v = table[idx[nc * 196 + m] * 16 + h];
    } else {
      v = -1e30f;
    }
    outb[e] = f2bf(v);
  }
}

// ---------------------------------------------------------------------------
// K-tile body: 4 phases, each {ds_read subtile; 1 stage-pair; barrier;
// lgkmcnt(0); setprio(1); 16 MFMA; setprio(0); [vmcnt gate]; barrier}.
// LDS map (u16): A buf b at b*16384, half h at +h*8192; B at +32768.
// Deep-slack stage schedule:
//   p0: A1(kt+1) -> OBUF h1      p1: B1(kt+1) -> OBUF h1, gate vmcnt(8)
//   p2: A0(kt+2) -> BUF  h0      p3: B0(kt+2) -> BUF  h0, gate vmcnt(8)
// Tail: kt=6 p3 gate vmcnt(4); kt=7 p1 gate vmcnt(0).
// ---------------------------------------------------------------------------
template<int KT>
__device__ __forceinline__ void ktile(u16* __restrict__ SMEM,
    const u16* __restrict__ gA0, const u16* __restrict__ gA1,
    const u16* __restrict__ gB0, const u16* __restrict__ gB1,
    int wbase, int rdA, int rdB, f32x4 (&acc)[8][4]) {
  constexpr int BUF = KT & 1, OBUF = BUF ^ 1;
  constexpr bool S01 = (KT < 7);               // stage T(kt+1) half1
  constexpr bool S23 = (KT < 6);               // stage T(kt+2) half0
  constexpr int C1 = (KT + 1) * 64;            // u16 col offset of T(kt+1)
  constexpr int C2 = (KT + 2) * 64;            // u16 col offset of T(kt+2)
  bf16x8 afr[4], bfr[4];

#define LOADPAIR(dst, g0, g1, coloff)                                          \
  __builtin_amdgcn_global_load_lds((const AS1 void*)((g0) + (coloff)),         \
      (AS3 void*)&SMEM[(dst) + wbase], 16, 0, 0);                              \
  __builtin_amdgcn_global_load_lds((const AS1 void*)((g1) + (coloff)),         \
      (AS3 void*)&SMEM[(dst) + 4096 + wbase], 16, 0, 0);
#define MFMA16(FH)                                                             \
  __builtin_amdgcn_s_setprio(1);                                               \
  _Pragma("unroll") for (int q = 0; q < 4; ++q)                                \
    _Pragma("unroll") for (int j = 0; j < 4; ++j)                              \
      acc[(FH)*4 + q][j] = __builtin_amdgcn_mfma_f32_16x16x32_bf16(            \
          afr[q], bfr[j], acc[(FH)*4 + q][j], 0, 0, 0);                        \
  __builtin_amdgcn_s_setprio(0);

  // ---- p0: ksub0, f0-3 ----
#pragma unroll
  for (int j = 0; j < 4; ++j) bfr[j] = *(const bf16x8*)&SMEM[rdB + BUF * 16384 + j * 512];
#pragma unroll
  for (int q = 0; q < 4; ++q) afr[q] = *(const bf16x8*)&SMEM[rdA + BUF * 16384 + q * 512];
  if constexpr (S01) { LOADPAIR(OBUF * 16384 + 8192, gA0, gA1, C1 + 32) }
  __builtin_amdgcn_s_barrier();
  asm volatile("s_waitcnt lgkmcnt(0)" ::: "memory");
  MFMA16(0)
  __builtin_amdgcn_s_barrier();
  // ---- p1: ksub0, f4-7 (bfr reused from registers) ----
#pragma unroll
  for (int q = 0; q < 4; ++q) afr[q] = *(const bf16x8*)&SMEM[rdA + BUF * 16384 + (q + 4) * 512];
  if constexpr (S01) { LOADPAIR(32768 + OBUF * 16384 + 8192, gB0, gB1, C1 + 32) }
  __builtin_amdgcn_s_barrier();
  asm volatile("s_waitcnt lgkmcnt(0)" ::: "memory");
  MFMA16(1)
  if constexpr (KT < 7) { asm volatile("s_waitcnt vmcnt(8)" ::: "memory"); }
  else                  { asm volatile("s_waitcnt vmcnt(0)" ::: "memory"); }
  __builtin_amdgcn_s_barrier();
  // ---- p2: ksub1, f0-3 ----
#pragma unroll
  for (int j = 0; j < 4; ++j) bfr[j] = *(const bf16x8*)&SMEM[rdB + BUF * 16384 + 8192 + j * 512];
#pragma unroll
  for (int q = 0; q < 4; ++q) afr[q] = *(const bf16x8*)&SMEM[rdA + BUF * 16384 + 8192 + q * 512];
  if constexpr (S23) { LOADPAIR(BUF * 16384, gA0, gA1, C2) }
  __builtin_amdgcn_s_barrier();
  asm volatile("s_waitcnt lgkmcnt(0)" ::: "memory");
  MFMA16(0)
  __builtin_amdgcn_s_barrier();
  // ---- p3: ksub1, f4-7 ----
#pragma unroll
  for (int q = 0; q < 4; ++q) afr[q] = *(const bf16x8*)&SMEM[rdA + BUF * 16384 + 8192 + (q + 4) * 512];
  if constexpr (S23) { LOADPAIR(32768 + BUF * 16384, gB0, gB1, C2) }
  __builtin_amdgcn_s_barrier();
  asm volatile("s_waitcnt lgkmcnt(0)" ::: "memory");
  MFMA16(1)
  if constexpr (KT < 6)       { asm volatile("s_waitcnt vmcnt(8)" ::: "memory"); }
  else if constexpr (KT == 6) { asm volatile("s_waitcnt vmcnt(4)" ::: "memory"); }
  __builtin_amdgcn_s_barrier();
#undef LOADPAIR
#undef MFMA16
}

// ---- 256x256 bf16 GEMM, C = A * Bt^T; deep-slack fine-phase pipeline ------
// EPI 0: qkv epilogue via LDS re-stage (all outputs row-major [bh][196][32])
// EPI 1: proj epilogue (+bias, row-contiguous nontemporal fp32 stores)
template<int EPI>
__global__ __launch_bounds__(512, 2) void gemm8p(
    const u16* __restrict__ A, const u16* __restrict__ Bt,
    u16* __restrict__ q, u16* __restrict__ kk, u16* __restrict__ vv,
    const float* __restrict__ pbias, float* __restrict__ out) {
  constexpr int NWGX = (EPI == 0) ? 6 : 2;
  constexpr int NWG = NWGX * 196;
  __shared__ __align__(16) u16 SMEM[65536];    // 128 KB

  int id = blockIdx.y * NWGX + blockIdx.x;
  int nf = (id & 7) * (NWG >> 3) + (id >> 3);  // XCD-chunked bijective swizzle
  const int bx = nf / NWGX, by = nf - (nf / NWGX) * NWGX;

  const int tid = threadIdx.x;
  const int w = tid >> 6, l = tid & 63;
  const int lr = l & 15, lg = l >> 4;
  const int wm = w >> 2, wn = w & 3;

  // staging sources: wave w covers rows w*16+(l>>2) (g*0) and +128 (g*1);
  // granule pre-swizzled so LDS slot s holds global granule s^((row>>1)&3)
  const int gsw = (l & 3) ^ ((l >> 3) & 3);
  const u16* gA0 = A + (size_t)(bx * 256 + w * 16 + (l >> 2)) * 512 + gsw * 8;
  const u16* gA1 = gA0 + 65536;                 // +128 rows
  const u16* gB0 = Bt + (size_t)(by * 256 + w * 16 + (l >> 2)) * 512 + gsw * 8;
  const u16* gB1 = gB0 + 65536;
  const int wbase = w * 512;                    // wave-uniform LDS dest base

  // ds_read bases (u16): row*32 + swizzled granule
  const int rsw = (lg ^ ((lr >> 1) & 3)) * 8;
  const int rdA = (wm * 128 + lr) * 32 + rsw;
  const int rdB = 32768 + (wn * 64 + lr) * 32 + rsw;

  f32x4 acc[8][4] = {};

  // prologue: 6 pinned pairs A0(0),B0(0),A1(0),B1(0),A0(1),B0(1); vmcnt(8)
#define PLP(dst, g0, g1, coloff)                                               \
  __builtin_amdgcn_global_load_lds((const AS1 void*)((g0) + (coloff)),         \
      (AS3 void*)&SMEM[(dst) + wbase], 16, 0, 0);                              \
  __builtin_amdgcn_global_load_lds((const AS1 void*)((g1) + (coloff)),         \
      (AS3 void*)&SMEM[(dst) + 4096 + wbase], 16, 0, 0);
  PLP(0, gA0, gA1, 0)                    // A0(k0) -> buf0 h0
  asm volatile("" ::: "memory");
  PLP(32768, gB0, gB1, 0)                // B0(k0)
  asm volatile("" ::: "memory");
  PLP(8192, gA0, gA1, 32)                // A1(k0) -> buf0 h1
  asm volatile("" ::: "memory");
  PLP(32768 + 8192, gB0, gB1, 32)        // B1(k0)
  asm volatile("" ::: "memory");
  PLP(16384, gA0, gA1, 64)               // A0(k1) -> buf1 h0
  asm volatile("" ::: "memory");
  PLP(32768 + 16384, gB0, gB1, 64)       // B0(k1)
#undef PLP
  asm volatile("s_waitcnt vmcnt(8)" ::: "memory");
  __builtin_amdgcn_s_barrier();

  ktile<0>(SMEM, gA0, gA1, gB0, gB1, wbase, rdA, rdB, acc);
  ktile<1>(SMEM, gA0, gA1, gB0, gB1, wbase, rdA, rdB, acc);
  ktile<2>(SMEM, gA0, gA1, gB0, gB1, wbase, rdA, rdB, acc);
  ktile<3>(SMEM, gA0, gA1, gB0, gB1, wbase, rdA, rdB, acc);
  ktile<4>(SMEM, gA0, gA1, gB0, gB1, wbase, rdA, rdB, acc);
  ktile<5>(SMEM, gA0, gA1, gB0, gB1, wbase, rdA, rdB, acc);
  ktile<6>(SMEM, gA0, gA1, gB0, gB1, wbase, rdA, rdB, acc);
  ktile<7>(SMEM, gA0, gA1, gB0, gB1, wbase, rdA, rdB, acc);

  if (EPI == 0) {
    // wg-uniform output: by 0,1 -> q; 2,3 -> k; 4,5 -> v (all [bh][196][32])
    const int t = by >> 1;
    u16* dst = (t == 0) ? q : (t == 1) ? kk : vv;
    const int colbase = by * 256;
    const float s = (t == 0) ? 0.17677669529663687f : 1.0f;  // 32^-0.5 into q
#pragma unroll
    for (int p = 0; p < 2; ++p) {   // pass p: global rows bx*256+p*128..+127
      __syncthreads();
      if (wm == p) {                 // row-major CT[128][264]
#pragma unroll
        for (int f = 0; f < 8; ++f)
#pragma unroll
          for (int j2 = 0; j2 < 4; ++j2)
#pragma unroll
            for (int r = 0; r < 4; ++r)
              SMEM[(f * 16 + lg * 4 + r) * 264 + wn * 64 + j2 * 16 + lr] =
                  f2bf(acc[f][j2][r] * s);
      }
      __syncthreads();
      const int growbase = bx * 256 + p * 128;
      const int lrow = tid >> 2, ch = tid & 3;
      const int grow = growbase + lrow;
      const int bb2 = grow / 196, nn = grow - bb2 * 196;
#pragma unroll
      for (int i = 0; i < 8; ++i) {
        const int colle = (ch + i * 4) * 8;          // strided granules
        bf16x8 vvx = *(const bf16x8*)&SMEM[lrow * 264 + colle];
        const int col = colbase + colle;
        const int h = (col >> 5) & 15, dd = col & 31;
        *(bf16x8*)&dst[((size_t)(bb2 * 16 + h) * 196 + nn) * 32 + dd] = vvx;
      }
    }
  } else {
    const int colbase = by * 256 + wn * 64;
    const int rowb = bx * 256 + wm * 128 + lg * 4;
    float pb4[4];
#pragma unroll
    for (int j2 = 0; j2 < 4; ++j2) pb4[j2] = pbias[colbase + j2 * 16 + lr];
#pragma unroll
    for (int f = 0; f < 8; ++f) {
      const int row0 = rowb + f * 16;
#pragma unroll
      for (int r = 0; r < 4; ++r) {
        // row-contiguous: the 4 segments of this row issue back-to-back
        float* orow = out + (size_t)(row0 + r) * 512 + colbase + lr;
#pragma unroll
        for (int j2 = 0; j2 < 4; ++j2)
          __builtin_nontemporal_store(acc[f][j2][r] + pb4[j2], orow + j2 * 16);
      }
    }
  }
}

// ---- fused attention per (b,h): swapped QK^T, in-register P, PV -----------
// Per-nt bias quads prefetched to a statically-indexed register array so the
// 14 L2 loads are all in flight together (latency-bound fix, r13 post-mortem).
__global__ __launch_bounds__(256, 4) void attn_kernel(
    const u16* __restrict__ q, const u16* __restrict__ kk,
    const u16* __restrict__ vv, const u16* __restrict__ biasA,
    u16* __restrict__ ao) {
  __shared__ u16 Ks[196 * 40];      // K rows (m), stride 40 (16B-aligned)
  __shared__ u16 Vs[32 * 232];      // V^T rows (d), stride 232, XOR-swizzled
  const int bhd = blockIdx.x;
  const int h = bhd >> 8, bb = bhd & 255;    // h-major: bias slice stays L2-hot
  const int bh = bb * 16 + h;
  const int tid = threadIdx.x, w = tid >> 6, l = tid & 63;
  const int lr = l & 15, lg = l >> 4;

  {
    const u16* kg = kk + (size_t)bh * (196 * 32);
    const u16* vg = vv + (size_t)bh * (196 * 32);
    // zero V^T pad (m in [196,232)), same swizzled addressing
    for (int k = tid; k < 32 * 36; k += 256) {
      int d = k / 36, m = 196 + (k - (k / 36) * 36);
      int g = m >> 3;
      int gs = (g < 28) ? (g ^ ((d >> 3) & 3)) : g;
      Vs[d * 232 + gs * 8 + (m & 7)] = 0;
    }
#pragma unroll
    for (int p = 0; p < 4; ++p) {
      int m = p * 64 + (tid >> 2);
      if (m < 196) {
        int c8 = (tid & 3) * 8;
        *(bf16x8*)&Ks[m * 40 + c8] = *(const bf16x8*)(kg + m * 32 + c8);
        bf16x8 v8 = *(const bf16x8*)(vg + m * 32 + c8);
        const int key = c8 >> 3;                    // (d>>3)&3 for d=c8+e
        const int gs = (m >> 3) ^ key;              // m<196 -> g<25, always XOR
#pragma unroll
        for (int e = 0; e < 8; ++e)
          Vs[(c8 + e) * 232 + gs * 8 + (m & 7)] = (u16)((short*)&v8)[e];
      }
    }
  }
  __syncthreads();

  const u16* biasH = biasA + (size_t)h * (13 * 14 * 256);
  const int sA = ((l & 16) << 1) + lr;   // src lane for k-slots j=0..3
  const int sB = sA + 16;                // src lane for k-slots j=4..7
  const bool hi = (l & 32) != 0;         // lg>=2 -> odd 16-tile of the ks pair
  const int key0 = lr >> 3;              // XOR key for d = lr
  const int key1 = 2 + (lr >> 3);        // XOR key for d = 16+lr

  for (int nt = w; nt < 13; nt += 4) {
    int nq = nt * 16 + lr; if (nq > 195) nq = 195;
    bf16x8 qa = *(const bf16x8*)(q + ((size_t)bh * 196 + nq) * 32 + lg * 8);

    // ---- prefetch all 14 bias quads (28 VGPRs, 14 L2 loads in flight) ----
    ushort4 b4s[14];
#pragma unroll
    for (int mt = 0; mt < 14; ++mt)
      b4s[mt] = *(const ushort4*)(biasH + ((nt * 14 + mt) * 64 + l) * 4);

    // ---- QK^T (swapped: mfma(K,Q)) fused with exp + bf16 pack ----
    u32 pk[14][2];
    float ssum = 0.f;
#pragma unroll
    for (int mt = 0; mt < 14; ++mt) {
      int row = mt * 16 + lr; if (row > 195) row = 195;  // pad rows masked via bias
      bf16x8 kb = *(const bf16x8*)&Ks[row * 40 + lg * 8];
      f32x4 c;
      c[0] = __uint_as_float(((u32)b4s[mt].x) << 16);
      c[1] = __uint_as_float(((u32)b4s[mt].y) << 16);
      c[2] = __uint_as_float(((u32)b4s[mt].z) << 16);
      c[3] = __uint_as_float(((u32)b4s[mt].w) << 16);
      f32x4 S = __builtin_amdgcn_mfma_f32_16x16x32_bf16(kb, qa, c, 0, 0, 0);
      // no max-pass: |S| small by construction; mask -1e30 -> exp == +0
      float e0 = __expf(S[0]), e1 = __expf(S[1]);
      float e2 = __expf(S[2]), e3 = __expf(S[3]);
      ssum += (e0 + e1) + (e2 + e3);
      asm("v_cvt_pk_bf16_f32 %0, %1, %2" : "=v"(pk[mt][0]) : "v"(e0), "v"(e1));
      asm("v_cvt_pk_bf16_f32 %0, %1, %2" : "=v"(pk[mt][1]) : "v"(e2), "v"(e3));
    }
    // row sum lives split across the 4 lane-groups of same lr
    ssum += __shfl_xor(ssum, 16);
    ssum += __shfl_xor(ssum, 32);
    float invT = __builtin_amdgcn_rcpf(ssum);   // 1/sum for row n = lr

    // ---- PV: rebuild A-fragment in-register via shuffles ----
    f32x4 O0 = {}, O1 = {};
#pragma unroll
    for (int ks = 0; ks < 7; ++ks) {
      u32 a0 = (u32)__shfl((int)pk[2 * ks][0], sA);
      u32 a1 = (u32)__shfl((int)pk[2 * ks][1], sA);
      u32 a2 = (u32)__shfl((int)pk[2 * ks][0], sB);
      u32 a3 = (u32)__shfl((int)pk[2 * ks][1], sB);
      u32 c0 = (u32)__shfl((int)pk[2 * ks + 1][0], sA);
      u32 c1 = (u32)__shfl((int)pk[2 * ks + 1][1], sA);
      u32 c2 = (u32)__shfl((int)pk[2 * ks + 1][0], sB);
      u32 c3 = (u32)__shfl((int)pk[2 * ks + 1][1], sB);
      bf16x8 pa;
      ((u32*)&pa)[0] = hi ? c0 : a0;
      ((u32*)&pa)[1] = hi ? c1 : a1;
      ((u32*)&pa)[2] = hi ? c2 : a2;
      ((u32*)&pa)[3] = hi ? c3 : a3;
      const int g = ks * 4 + lg;                  // source granule (<28)
      bf16x8 v0 = *(const bf16x8*)&Vs[lr * 232 + (g ^ key0) * 8];
      bf16x8 v1 = *(const bf16x8*)&Vs[(16 + lr) * 232 + (g ^ key1) * 8];
      O0 = __builtin_amdgcn_mfma_f32_16x16x32_bf16(pa, v0, O0, 0, 0, 0);
      O1 = __builtin_amdgcn_mfma_f32_16x16x32_bf16(pa, v1, O1, 0, 0, 0);
    }

    // ---- epilogue: fetch 1/sum for own output rows, scale, store ----
    float inv[4];
#pragma unroll
    for (int r = 0; r < 4; ++r) inv[r] = __shfl(invT, lg * 4 + r);
    const int nr0 = nt * 16 + lg * 4;
#pragma unroll
    for (int r = 0; r < 4; ++r) {
      int nr = nr0 + r;
      if (nr < 196) {
        size_t base = ((size_t)bb * 196 + nr) * 512 + h * 32;
        ao[base + lr] = f2bf(O0[r] * inv[r]);
        ao[base + 16 + lr] = f2bf(O1[r] * inv[r]);
      }
    }
  }
}

extern "C" void kernel_launch(void* const* d_in, const int* in_sizes, int n_in,
                              void* d_out, int out_size, void* d_ws, size_t ws_size,
                              hipStream_t stream) {
  const float* x      = (const float*)d_in[0];
  const float* qkv_w  = (const float*)d_in[1];
  const float* proj_w = (const float*)d_in[2];
  const float* proj_b = (const float*)d_in[3];
  const float* table  = (const float*)d_in[4];
  const int*   ridx   = (const int*)d_in[5];
  float* out = (float*)d_out;

  char* ws = (char*)d_ws;
  u16*   xb    = (u16*)(ws);                  // also attn_out after GEMM1 use
  u16*   qwb   = (u16*)(ws + 51380224);
  u16*   pwb   = (u16*)(ws + 52953088);
  u16*   qb    = (u16*)(ws + 53477376);
  u16*   kb    = (u16*)(ws + 104857600);
  u16*   vb    = (u16*)(ws + 156237824);
  u16*   biasA = (u16*)(ws + 217055232);

  prep_fused<<<29024, 256, 0, stream>>>(x, qkv_w, proj_w, table, ridx,
                                        xb, qwb, pwb, biasA);

  gemm8p<0><<<dim3(6, 196), 512, 0, stream>>>(xb, qwb, qb, kb, vb, nullptr, nullptr);
  attn_kernel<<<4096, 256, 0, stream>>>(qb, kb, vb, biasA, xb /* attn_out alias */);
  gemm8p<1><<<dim3(2, 196), 512, 0, stream>>>(xb, pwb, nullptr, nullptr, nullptr, proj_b, out);
}

// Round 17
// 260.995 us; speedup vs baseline: 1.0173x; 1.0173x over previous
//
#include <hip/hip_runtime.h>
#include <hip/hip_bf16.h>

// ---------------------------------------------------------------------------
// QuantAttention: x[256,196,512] -> qkv -> windowed attn (+rel-pos bias) -> proj
// bf16 MFMA everywhere. GEMMs: 256x256 tile, BK=64 K-tiles, 4 fine phases per
// K-tile, deep-slack counted vmcnt(8) staging, XOR-swizzled LDS, setprio.
// qkv outputs row-major [bh][196][32]; attn transposes V into LDS with a
// granule-XOR swizzle; per-nt bias quads prefetched into registers.
// Prologue (3x cvt + bias gather) fused into ONE kernel (launch overhead).
// Workspace layout:
//   [0)            x_bf16 (aliased later as attn_out bf16)   51,380,224 B
//   [51380224)     qkv_w bf16                                 1,572,864 B
//   [52953088)     proj_w bf16                                  524,288 B
//   [53477376)     q bf16 [bh][196][32] (scale folded)       51,380,224 B
//   [104857600)    k bf16 [bh][196][32]                      51,380,224 B
//   [156237824)    v bf16 [bh][196][32]                      51,380,224 B
//   [217055232)    bias bf16 [h][13][14][64][4] (swapped)     1,490,944 B
// ---------------------------------------------------------------------------

typedef unsigned short u16;
typedef unsigned int u32;
typedef __attribute__((ext_vector_type(8))) short bf16x8;
typedef __attribute__((ext_vector_type(4))) float f32x4;

#define AS1 __attribute__((address_space(1)))
#define AS3 __attribute__((address_space(3)))

__device__ __forceinline__ u16 f2bf(float f) {
  union { float f; unsigned u; } c; c.f = f;
  unsigned r = ((c.u >> 16) & 1u) + 0x7fffu;   // round-to-nearest-even
  return (u16)((c.u + r) >> 16);
}

__device__ __forceinline__ void cvt4(const float* __restrict__ in,
                                     u16* __restrict__ out, int i, int n) {
  if (i >= n) return;
  float4 v = *(const float4*)(in + i);
  ushort4 o;
  o.x = f2bf(v.x); o.y = f2bf(v.y); o.z = f2bf(v.z); o.w = f2bf(v.w);
  *(ushort4*)(out + i) = o;
}

// ---- fused prologue: cvt x / qkv_w / proj_w + rel-pos bias pre-gather -----
// blocks [0,25088): x; [25088,25856): qkv_w; [25856,26112): proj_w;
// [26112,29024): bias bf16 [h][13][14][64][4] in SWAPPED C-frag order
// (n = nt*16+(lane&15) clamped, m = mt*16+(lane>>4)*4+r; m>=196 -> -1e30).
__global__ __launch_bounds__(256) void prep_fused(
    const float* __restrict__ x, const float* __restrict__ qkv_w,
    const float* __restrict__ proj_w, const float* __restrict__ table,
    const int* __restrict__ idx, u16* __restrict__ xb, u16* __restrict__ qwb,
    u16* __restrict__ pwb, u16* __restrict__ outb) {
  const int b = blockIdx.x, tid = threadIdx.x;
  if (b < 25088) {
    cvt4(x, xb, (b * 256 + tid) * 4, 25690112);
  } else if (b < 25856) {
    cvt4(qkv_w, qwb, ((b - 25088) * 256 + tid) * 4, 786432);
  } else if (b < 26112) {
    cvt4(proj_w, pwb, ((b - 25856) * 256 + tid) * 4, 262144);
  } else {
    int e = (b - 26112) * 256 + tid;           // < 745472
    int r = e & 3, lane = (e >> 2) & 63, rest = e >> 8;
    int mt = rest % 14; rest /= 14;
    int nt = rest % 13; int h = rest / 13;
    int n = nt * 16 + (lane & 15);
    int m = mt * 16 + ((lane >> 4) << 2) + r;
    float v;
    if (m < 196) {
      int nc = n < 196 ? n : 195;
      v = table[idx[nc * 196 + m] * 16 + h];
    } else {
      v = -1e30f;
    }
    outb[e] = f2bf(v);
  }
}

// ---------------------------------------------------------------------------
// K-tile body: 4 phases, each {ds_read subtile; 1 stage-pair; barrier;
// lgkmcnt(0); setprio(1); 16 MFMA; setprio(0); [vmcnt gate]; barrier}.
// LDS map (u16): A buf b at b*16384, half h at +h*8192; B at +32768.
// Deep-slack stage schedule:
//   p0: A1(kt+1) -> OBUF h1      p1: B1(kt+1) -> OBUF h1, gate vmcnt(8)
//   p2: A0(kt+2) -> BUF  h0      p3: B0(kt+2) -> BUF  h0, gate vmcnt(8)
// Tail: kt=6 p3 gate vmcnt(4); kt=7 p1 gate vmcnt(0).
// ---------------------------------------------------------------------------
template<int KT>
__device__ __forceinline__ void ktile(u16* __restrict__ SMEM,
    const u16* __restrict__ gA0, const u16* __restrict__ gA1,
    const u16* __restrict__ gB0, const u16* __restrict__ gB1,
    int wbase, int rdA, int rdB, f32x4 (&acc)[8][4]) {
  constexpr int BUF = KT & 1, OBUF = BUF ^ 1;
  constexpr bool S01 = (KT < 7);               // stage T(kt+1) half1
  constexpr bool S23 = (KT < 6);               // stage T(kt+2) half0
  constexpr int C1 = (KT + 1) * 64;            // u16 col offset of T(kt+1)
  constexpr int C2 = (KT + 2) * 64;            // u16 col offset of T(kt+2)
  bf16x8 afr[4], bfr[4];

#define LOADPAIR(dst, g0, g1, coloff)                                          \
  __builtin_amdgcn_global_load_lds((const AS1 void*)((g0) + (coloff)),         \
      (AS3 void*)&SMEM[(dst) + wbase], 16, 0, 0);                              \
  __builtin_amdgcn_global_load_lds((const AS1 void*)((g1) + (coloff)),         \
      (AS3 void*)&SMEM[(dst) + 4096 + wbase], 16, 0, 0);
#define MFMA16(FH)                                                             \
  __builtin_amdgcn_s_setprio(1);                                               \
  _Pragma("unroll") for (int q = 0; q < 4; ++q)                                \
    _Pragma("unroll") for (int j = 0; j < 4; ++j)                              \
      acc[(FH)*4 + q][j] = __builtin_amdgcn_mfma_f32_16x16x32_bf16(            \
          afr[q], bfr[j], acc[(FH)*4 + q][j], 0, 0, 0);                        \
  __builtin_amdgcn_s_setprio(0);

  // ---- p0: ksub0, f0-3 ----
#pragma unroll
  for (int j = 0; j < 4; ++j) bfr[j] = *(const bf16x8*)&SMEM[rdB + BUF * 16384 + j * 512];
#pragma unroll
  for (int q = 0; q < 4; ++q) afr[q] = *(const bf16x8*)&SMEM[rdA + BUF * 16384 + q * 512];
  if constexpr (S01) { LOADPAIR(OBUF * 16384 + 8192, gA0, gA1, C1 + 32) }
  __builtin_amdgcn_s_barrier();
  asm volatile("s_waitcnt lgkmcnt(0)" ::: "memory");
  MFMA16(0)
  __builtin_amdgcn_s_barrier();
  // ---- p1: ksub0, f4-7 (bfr reused from registers) ----
#pragma unroll
  for (int q = 0; q < 4; ++q) afr[q] = *(const bf16x8*)&SMEM[rdA + BUF * 16384 + (q + 4) * 512];
  if constexpr (S01) { LOADPAIR(32768 + OBUF * 16384 + 8192, gB0, gB1, C1 + 32) }
  __builtin_amdgcn_s_barrier();
  asm volatile("s_waitcnt lgkmcnt(0)" ::: "memory");
  MFMA16(1)
  if constexpr (KT < 7) { asm volatile("s_waitcnt vmcnt(8)" ::: "memory"); }
  else                  { asm volatile("s_waitcnt vmcnt(0)" ::: "memory"); }
  __builtin_amdgcn_s_barrier();
  // ---- p2: ksub1, f0-3 ----
#pragma unroll
  for (int j = 0; j < 4; ++j) bfr[j] = *(const bf16x8*)&SMEM[rdB + BUF * 16384 + 8192 + j * 512];
#pragma unroll
  for (int q = 0; q < 4; ++q) afr[q] = *(const bf16x8*)&SMEM[rdA + BUF * 16384 + 8192 + q * 512];
  if constexpr (S23) { LOADPAIR(BUF * 16384, gA0, gA1, C2) }
  __builtin_amdgcn_s_barrier();
  asm volatile("s_waitcnt lgkmcnt(0)" ::: "memory");
  MFMA16(0)
  __builtin_amdgcn_s_barrier();
  // ---- p3: ksub1, f4-7 ----
#pragma unroll
  for (int q = 0; q < 4; ++q) afr[q] = *(const bf16x8*)&SMEM[rdA + BUF * 16384 + 8192 + (q + 4) * 512];
  if constexpr (S23) { LOADPAIR(32768 + BUF * 16384, gB0, gB1, C2) }
  __builtin_amdgcn_s_barrier();
  asm volatile("s_waitcnt lgkmcnt(0)" ::: "memory");
  MFMA16(1)
  if constexpr (KT < 6)       { asm volatile("s_waitcnt vmcnt(8)" ::: "memory"); }
  else if constexpr (KT == 6) { asm volatile("s_waitcnt vmcnt(4)" ::: "memory"); }
  __builtin_amdgcn_s_barrier();
#undef LOADPAIR
#undef MFMA16
}

// ---- 256x256 bf16 GEMM, C = A * Bt^T; deep-slack fine-phase pipeline ------
// EPI 0: qkv epilogue via LDS re-stage (all outputs row-major [bh][196][32])
// EPI 1: proj epilogue (+bias, fp32 direct stores)
template<int EPI>
__global__ __launch_bounds__(512, 2) void gemm8p(
    const u16* __restrict__ A, const u16* __restrict__ Bt,
    u16* __restrict__ q, u16* __restrict__ kk, u16* __restrict__ vv,
    const float* __restrict__ pbias, float* __restrict__ out) {
  constexpr int NWGX = (EPI == 0) ? 6 : 2;
  constexpr int NWG = NWGX * 196;
  __shared__ __align__(16) u16 SMEM[65536];    // 128 KB

  int id = blockIdx.y * NWGX + blockIdx.x;
  int nf = (id & 7) * (NWG >> 3) + (id >> 3);  // XCD-chunked bijective swizzle
  const int bx = nf / NWGX, by = nf - (nf / NWGX) * NWGX;

  const int tid = threadIdx.x;
  const int w = tid >> 6, l = tid & 63;
  const int lr = l & 15, lg = l >> 4;
  const int wm = w >> 2, wn = w & 3;

  // staging sources: wave w covers rows w*16+(l>>2) (g*0) and +128 (g*1);
  // granule pre-swizzled so LDS slot s holds global granule s^((row>>1)&3)
  const int gsw = (l & 3) ^ ((l >> 3) & 3);
  const u16* gA0 = A + (size_t)(bx * 256 + w * 16 + (l >> 2)) * 512 + gsw * 8;
  const u16* gA1 = gA0 + 65536;                 // +128 rows
  const u16* gB0 = Bt + (size_t)(by * 256 + w * 16 + (l >> 2)) * 512 + gsw * 8;
  const u16* gB1 = gB0 + 65536;
  const int wbase = w * 512;                    // wave-uniform LDS dest base

  // ds_read bases (u16): row*32 + swizzled granule
  const int rsw = (lg ^ ((lr >> 1) & 3)) * 8;
  const int rdA = (wm * 128 + lr) * 32 + rsw;
  const int rdB = 32768 + (wn * 64 + lr) * 32 + rsw;

  f32x4 acc[8][4] = {};

  // prologue: 6 pinned pairs A0(0),B0(0),A1(0),B1(0),A0(1),B0(1); vmcnt(8)
#define PLP(dst, g0, g1, coloff)                                               \
  __builtin_amdgcn_global_load_lds((const AS1 void*)((g0) + (coloff)),         \
      (AS3 void*)&SMEM[(dst) + wbase], 16, 0, 0);                              \
  __builtin_amdgcn_global_load_lds((const AS1 void*)((g1) + (coloff)),         \
      (AS3 void*)&SMEM[(dst) + 4096 + wbase], 16, 0, 0);
  PLP(0, gA0, gA1, 0)                    // A0(k0) -> buf0 h0
  asm volatile("" ::: "memory");
  PLP(32768, gB0, gB1, 0)                // B0(k0)
  asm volatile("" ::: "memory");
  PLP(8192, gA0, gA1, 32)                // A1(k0) -> buf0 h1
  asm volatile("" ::: "memory");
  PLP(32768 + 8192, gB0, gB1, 32)        // B1(k0)
  asm volatile("" ::: "memory");
  PLP(16384, gA0, gA1, 64)               // A0(k1) -> buf1 h0
  asm volatile("" ::: "memory");
  PLP(32768 + 16384, gB0, gB1, 64)       // B0(k1)
#undef PLP
  asm volatile("s_waitcnt vmcnt(8)" ::: "memory");
  __builtin_amdgcn_s_barrier();

  ktile<0>(SMEM, gA0, gA1, gB0, gB1, wbase, rdA, rdB, acc);
  ktile<1>(SMEM, gA0, gA1, gB0, gB1, wbase, rdA, rdB, acc);
  ktile<2>(SMEM, gA0, gA1, gB0, gB1, wbase, rdA, rdB, acc);
  ktile<3>(SMEM, gA0, gA1, gB0, gB1, wbase, rdA, rdB, acc);
  ktile<4>(SMEM, gA0, gA1, gB0, gB1, wbase, rdA, rdB, acc);
  ktile<5>(SMEM, gA0, gA1, gB0, gB1, wbase, rdA, rdB, acc);
  ktile<6>(SMEM, gA0, gA1, gB0, gB1, wbase, rdA, rdB, acc);
  ktile<7>(SMEM, gA0, gA1, gB0, gB1, wbase, rdA, rdB, acc);

  if (EPI == 0) {
    // wg-uniform output: by 0,1 -> q; 2,3 -> k; 4,5 -> v (all [bh][196][32])
    const int t = by >> 1;
    u16* dst = (t == 0) ? q : (t == 1) ? kk : vv;
    const int colbase = by * 256;
    const float s = (t == 0) ? 0.17677669529663687f : 1.0f;  // 32^-0.5 into q
#pragma unroll
    for (int p = 0; p < 2; ++p) {   // pass p: global rows bx*256+p*128..+127
      __syncthreads();
      if (wm == p) {                 // row-major CT[128][264]
#pragma unroll
        for (int f = 0; f < 8; ++f)
#pragma unroll
          for (int j2 = 0; j2 < 4; ++j2)
#pragma unroll
            for (int r = 0; r < 4; ++r)
              SMEM[(f * 16 + lg * 4 + r) * 264 + wn * 64 + j2 * 16 + lr] =
                  f2bf(acc[f][j2][r] * s);
      }
      __syncthreads();
      const int growbase = bx * 256 + p * 128;
      const int lrow = tid >> 2, ch = tid & 3;
      const int grow = growbase + lrow;
      const int bb2 = grow / 196, nn = grow - bb2 * 196;
#pragma unroll
      for (int i = 0; i < 8; ++i) {
        const int colle = (ch + i * 4) * 8;          // strided granules
        bf16x8 vvx = *(const bf16x8*)&SMEM[lrow * 264 + colle];
        const int col = colbase + colle;
        const int h = (col >> 5) & 15, dd = col & 31;
        *(bf16x8*)&dst[((size_t)(bb2 * 16 + h) * 196 + nn) * 32 + dd] = vvx;
      }
    }
  } else {
    const int colbase = by * 256 + wn * 64;
    const int rowb = bx * 256 + wm * 128 + lg * 4;
#pragma unroll
    for (int f = 0; f < 8; ++f) {
      const int row0 = rowb + f * 16;
#pragma unroll
      for (int j2 = 0; j2 < 4; ++j2) {
        const int col = colbase + j2 * 16 + lr;
        const float pb = pbias[col];
#pragma unroll
        for (int r = 0; r < 4; ++r)
          out[(size_t)(row0 + r) * 512 + col] = acc[f][j2][r] + pb;
      }
    }
  }
}

// ---- fused attention per (b,h): swapped QK^T, in-register P, PV -----------
// Per-nt bias quads prefetched to a statically-indexed register array so the
// 14 L2 loads are all in flight together (latency-bound fix, r13 post-mortem).
__global__ __launch_bounds__(256, 4) void attn_kernel(
    const u16* __restrict__ q, const u16* __restrict__ kk,
    const u16* __restrict__ vv, const u16* __restrict__ biasA,
    u16* __restrict__ ao) {
  __shared__ u16 Ks[196 * 40];      // K rows (m), stride 40 (16B-aligned)
  __shared__ u16 Vs[32 * 232];      // V^T rows (d), stride 232, XOR-swizzled
  const int bhd = blockIdx.x;
  const int h = bhd >> 8, bb = bhd & 255;    // h-major: bias slice stays L2-hot
  const int bh = bb * 16 + h;
  const int tid = threadIdx.x, w = tid >> 6, l = tid & 63;
  const int lr = l & 15, lg = l >> 4;

  {
    const u16* kg = kk + (size_t)bh * (196 * 32);
    const u16* vg = vv + (size_t)bh * (196 * 32);
    // zero V^T pad (m in [196,232)), same swizzled addressing
    for (int k = tid; k < 32 * 36; k += 256) {
      int d = k / 36, m = 196 + (k - (k / 36) * 36);
      int g = m >> 3;
      int gs = (g < 28) ? (g ^ ((d >> 3) & 3)) : g;
      Vs[d * 232 + gs * 8 + (m & 7)] = 0;
    }
#pragma unroll
    for (int p = 0; p < 4; ++p) {
      int m = p * 64 + (tid >> 2);
      if (m < 196) {
        int c8 = (tid & 3) * 8;
        *(bf16x8*)&Ks[m * 40 + c8] = *(const bf16x8*)(kg + m * 32 + c8);
        bf16x8 v8 = *(const bf16x8*)(vg + m * 32 + c8);
        const int key = c8 >> 3;                    // (d>>3)&3 for d=c8+e
        const int gs = (m >> 3) ^ key;              // m<196 -> g<25, always XOR
#pragma unroll
        for (int e = 0; e < 8; ++e)
          Vs[(c8 + e) * 232 + gs * 8 + (m & 7)] = (u16)((short*)&v8)[e];
      }
    }
  }
  __syncthreads();

  const u16* biasH = biasA + (size_t)h * (13 * 14 * 256);
  const int sA = ((l & 16) << 1) + lr;   // src lane for k-slots j=0..3
  const int sB = sA + 16;                // src lane for k-slots j=4..7
  const bool hi = (l & 32) != 0;         // lg>=2 -> odd 16-tile of the ks pair
  const int key0 = lr >> 3;              // XOR key for d = lr
  const int key1 = 2 + (lr >> 3);        // XOR key for d = 16+lr

  for (int nt = w; nt < 13; nt += 4) {
    int nq = nt * 16 + lr; if (nq > 195) nq = 195;
    bf16x8 qa = *(const bf16x8*)(q + ((size_t)bh * 196 + nq) * 32 + lg * 8);

    // ---- prefetch all 14 bias quads (28 VGPRs, 14 L2 loads in flight) ----
    ushort4 b4s[14];
#pragma unroll
    for (int mt = 0; mt < 14; ++mt)
      b4s[mt] = *(const ushort4*)(biasH + ((nt * 14 + mt) * 64 + l) * 4);

    // ---- QK^T (swapped: mfma(K,Q)) fused with exp + bf16 pack ----
    u32 pk[14][2];
    float ssum = 0.f;
#pragma unroll
    for (int mt = 0; mt < 14; ++mt) {
      int row = mt * 16 + lr; if (row > 195) row = 195;  // pad rows masked via bias
      bf16x8 kb = *(const bf16x8*)&Ks[row * 40 + lg * 8];
      f32x4 c;
      c[0] = __uint_as_float(((u32)b4s[mt].x) << 16);
      c[1] = __uint_as_float(((u32)b4s[mt].y) << 16);
      c[2] = __uint_as_float(((u32)b4s[mt].z) << 16);
      c[3] = __uint_as_float(((u32)b4s[mt].w) << 16);
      f32x4 S = __builtin_amdgcn_mfma_f32_16x16x32_bf16(kb, qa, c, 0, 0, 0);
      // no max-pass: |S| small by construction; mask -1e30 -> exp == +0
      float e0 = __expf(S[0]), e1 = __expf(S[1]);
      float e2 = __expf(S[2]), e3 = __expf(S[3]);
      ssum += (e0 + e1) + (e2 + e3);
      asm("v_cvt_pk_bf16_f32 %0, %1, %2" : "=v"(pk[mt][0]) : "v"(e0), "v"(e1));
      asm("v_cvt_pk_bf16_f32 %0, %1, %2" : "=v"(pk[mt][1]) : "v"(e2), "v"(e3));
    }
    // row sum lives split across the 4 lane-groups of same lr
    ssum += __shfl_xor(ssum, 16);
    ssum += __shfl_xor(ssum, 32);
    float invT = __builtin_amdgcn_rcpf(ssum);   // 1/sum for row n = lr

    // ---- PV: rebuild A-fragment in-register via shuffles ----
    f32x4 O0 = {}, O1 = {};
#pragma unroll
    for (int ks = 0; ks < 7; ++ks) {
      u32 a0 = (u32)__shfl((int)pk[2 * ks][0], sA);
      u32 a1 = (u32)__shfl((int)pk[2 * ks][1], sA);
      u32 a2 = (u32)__shfl((int)pk[2 * ks][0], sB);
      u32 a3 = (u32)__shfl((int)pk[2 * ks][1], sB);
      u32 c0 = (u32)__shfl((int)pk[2 * ks + 1][0], sA);
      u32 c1 = (u32)__shfl((int)pk[2 * ks + 1][1], sA);
      u32 c2 = (u32)__shfl((int)pk[2 * ks + 1][0], sB);
      u32 c3 = (u32)__shfl((int)pk[2 * ks + 1][1], sB);
      bf16x8 pa;
      ((u32*)&pa)[0] = hi ? c0 : a0;
      ((u32*)&pa)[1] = hi ? c1 : a1;
      ((u32*)&pa)[2] = hi ? c2 : a2;
      ((u32*)&pa)[3] = hi ? c3 : a3;
      const int g = ks * 4 + lg;                  // source granule (<28)
      bf16x8 v0 = *(const bf16x8*)&Vs[lr * 232 + (g ^ key0) * 8];
      bf16x8 v1 = *(const bf16x8*)&Vs[(16 + lr) * 232 + (g ^ key1) * 8];
      O0 = __builtin_amdgcn_mfma_f32_16x16x32_bf16(pa, v0, O0, 0, 0, 0);
      O1 = __builtin_amdgcn_mfma_f32_16x16x32_bf16(pa, v1, O1, 0, 0, 0);
    }

    // ---- epilogue: fetch 1/sum for own output rows, scale, store ----
    float inv[4];
#pragma unroll
    for (int r = 0; r < 4; ++r) inv[r] = __shfl(invT, lg * 4 + r);
    const int nr0 = nt * 16 + lg * 4;
#pragma unroll
    for (int r = 0; r < 4; ++r) {
      int nr = nr0 + r;
      if (nr < 196) {
        size_t base = ((size_t)bb * 196 + nr) * 512 + h * 32;
        ao[base + lr] = f2bf(O0[r] * inv[r]);
        ao[base + 16 + lr] = f2bf(O1[r] * inv[r]);
      }
    }
  }
}

extern "C" void kernel_launch(void* const* d_in, const int* in_sizes, int n_in,
                              void* d_out, int out_size, void* d_ws, size_t ws_size,
                              hipStream_t stream) {
  const float* x      = (const float*)d_in[0];
  const float* qkv_w  = (const float*)d_in[1];
  const float* proj_w = (const float*)d_in[2];
  const float* proj_b = (const float*)d_in[3];
  const float* table  = (const float*)d_in[4];
  const int*   ridx   = (const int*)d_in[5];
  float* out = (float*)d_out;

  char* ws = (char*)d_ws;
  u16*   xb    = (u16*)(ws);                  // also attn_out after GEMM1 use
  u16*   qwb   = (u16*)(ws + 51380224);
  u16*   pwb   = (u16*)(ws + 52953088);
  u16*   qb    = (u16*)(ws + 53477376);
  u16*   kb    = (u16*)(ws + 104857600);
  u16*   vb    = (u16*)(ws + 156237824);
  u16*   biasA = (u16*)(ws + 217055232);

  prep_fused<<<29024, 256, 0, stream>>>(x, qkv_w, proj_w, table, ridx,
                                        xb, qwb, pwb, biasA);

  gemm8p<0><<<dim3(6, 196), 512, 0, stream>>>(xb, qwb, qb, kb, vb, nullptr, nullptr);
  attn_kernel<<<4096, 256, 0, stream>>>(qb, kb, vb, biasA, xb /* attn_out alias */);
  gemm8p<1><<<dim3(2, 196), 512, 0, stream>>>(xb, pwb, nullptr, nullptr, nullptr, proj_b, out);
}